// Round 12
// baseline (372.460 us; speedup 1.0000x reference)
//
#include <hip/hip_runtime.h>

// Problem constants (fixed by setup_inputs)
#define NPG 200      // nodes per graph
#define EPG 1600     // edges per graph
#define DIM 200      // hidden size
#define NCLS 20      // classes
#define NGRAPH 256
#define THREADS 1024
#define NWAVES 16
#define NPB 100      // dst nodes per gather block (half graph)
#define Q4 50        // float4 lanes per row (DIM/4)
#define REPS 4       // amplification for ablation variants
#define NEG_INF (-__builtin_inff())

// MODE 0: real (1 rep, exact R6).  MODE 1: full x4.  MODE 2: L1-hit addr x4.
// MODE 3: loads live, no PROC x4.
template<int MODE>
__device__ __forceinline__ void gather_body(
    const float* __restrict__ node_emb, const float* __restrict__ edge_w,
    const int* __restrict__ node_ids, const int* __restrict__ edge_src,
    const int* __restrict__ edge_dst, const int* __restrict__ edge_ids,
    float* __restrict__ partial)
{
    __shared__ int            nidb[NPG];       // global row BYTE offset per local node
    __shared__ unsigned short srcl[EPG];
    __shared__ unsigned short dstl[EPG];
    __shared__ float          wv[EPG];
    __shared__ uint2          ce[EPG];         // CSR: {row_byte_off | ns_bit, w bits}
    __shared__ int            csum[128];
    __shared__ int            cursor[NPB];
    __shared__ short          wstart[NWAVES + 1];
    __shared__ float          part[NWAVES][DIM];

    const int bid = blockIdx.x;
    const int g   = bid & (NGRAPH - 1);
    const int h   = bid >> 8;
    const int n0g = h * NPB;
    const int tid = threadIdx.x;
    const int gbase_n = g * NPG;
    const int gbase_e = g * EPG;

    if (tid < NPG) nidb[tid] = node_ids[gbase_n + tid] * (DIM * 4);
    if (tid < 128) csum[tid] = 0;
    __syncthreads();

    // ---- prologue: edge staging + in-degree count (own dst range)
    for (int e = tid; e < EPG; e += THREADS) {
        int s  = edge_src[gbase_e + e] - gbase_n;
        int dl = edge_dst[gbase_e + e] - gbase_n;
        srcl[e] = (unsigned short)s;
        dstl[e] = (unsigned short)dl;
        int n = dl - n0g;
        if ((unsigned)n < NPB) {
            wv[e] = edge_w[edge_ids[gbase_e + e]];
            atomicAdd(&csum[n], 1);
        }
    }
    __syncthreads();

    if (tid < 64) {
        int2 c = *reinterpret_cast<int2*>(&csum[tid * 2]);
        int s1 = c.x + c.y;
        int carry = s1;
        #pragma unroll
        for (int off = 1; off < 64; off <<= 1) {
            int t = __shfl_up(carry, off);
            if (tid >= off) carry += t;
        }
        int base = carry - s1;
        int2 o; o.x = base + c.x; o.y = base + s1;
        *reinterpret_cast<int2*>(&csum[tid * 2]) = o;
    }
    __syncthreads();

    const int total = csum[NPB - 1];
    if (tid < NPB) cursor[tid] = (tid == 0) ? 0 : csum[tid - 1];
    if (tid <= NWAVES) {
        int target = (tid * total) >> 4;
        int lo = 0, hi = NPB;
        while (lo < hi) {
            int mid = (lo + hi) >> 1;
            int excl = mid ? csum[mid - 1] : 0;
            if (excl >= target) hi = mid; else lo = mid + 1;
        }
        wstart[tid] = (short)lo;
    }
    __syncthreads();

    for (int e = tid; e < EPG; e += THREADS) {
        int n = (int)dstl[e] - n0g;
        if ((unsigned)n < NPB) {
            int excl = n ? csum[n - 1] : 0;
            int pos  = atomicAdd(&cursor[n], 1);
            unsigned pack = (unsigned)nidb[srcl[e]] | (pos == excl ? 1u : 0u);
            ce[pos] = make_uint2(pack, __float_as_uint(wv[e]));
        }
    }
    __syncthreads();

    // ---- main loop (ablation target)
    const int w    = tid >> 6;
    const int lane = tid & 63;
    if (lane < Q4) {
        const int a0 = wstart[w];
        const int a1 = wstart[w + 1];
        const int kb = a0 ? csum[a0 - 1] : 0;
        const int ke = a1 ? csum[a1 - 1] : 0;
        const char* lb = (const char*)node_emb + lane * 16;

        float4 p = make_float4(0.f, 0.f, 0.f, 0.f);
        const int nrep = (MODE == 0) ? 1 : REPS;
        for (int rep = 0; rep < nrep; ++rep) {
            int ofs = 0;
            if (MODE != 0) asm volatile("" : "+v"(ofs));   // opaque 0: defeat cross-rep CSE
            float4 m = make_float4(0.f, 0.f, 0.f, 0.f);

            #pragma unroll 8
            for (int k = kb; k < ke; ++k) {
                const uint2 q2  = ce[k];
                const bool  ns  = (q2.x & 1u);
                const float wgt = __uint_as_float(q2.y);
                const char* ap  = (MODE == 2) ? (lb + ofs)
                                              : (lb + (int)(q2.x & ~1u) + ofs);
                const float4 v  = *reinterpret_cast<const float4*>(ap);
                if (MODE == 3) {
                    asm volatile("" :: "v"(v.x), "v"(v.y), "v"(v.z), "v"(v.w));
                } else {
                    p.x += ns ? m.x : 0.0f;  p.y += ns ? m.y : 0.0f;
                    p.z += ns ? m.z : 0.0f;  p.w += ns ? m.w : 0.0f;
                    m.x = fmaxf(ns ? NEG_INF : m.x, v.x * wgt);
                    m.y = fmaxf(ns ? NEG_INF : m.y, v.y * wgt);
                    m.z = fmaxf(ns ? NEG_INF : m.z, v.z * wgt);
                    m.w = fmaxf(ns ? NEG_INF : m.w, v.w * wgt);
                }
            }
            p.x += m.x; p.y += m.y; p.z += m.z; p.w += m.w;
        }
        *reinterpret_cast<float4*>(&part[w][lane * 4]) = p;
    }
    __syncthreads();

    if (tid < DIM) {
        float t = 0.f;
        #pragma unroll
        for (int i = 0; i < NWAVES; ++i) t += part[i][tid];
        partial[(MODE * 2 * NGRAPH + bid) * DIM + tid] = t;
    }
}

#define ARGS  const float* __restrict__ a, const float* __restrict__ b,            \
              const int* __restrict__ c, const int* __restrict__ d,                \
              const int* __restrict__ e, const int* __restrict__ f,                \
              float* __restrict__ p
__global__ __launch_bounds__(THREADS, 8) void g_real  (ARGS) { gather_body<0>(a,b,c,d,e,f,p); }
__global__ __launch_bounds__(THREADS, 8) void g_v1full(ARGS) { gather_body<1>(a,b,c,d,e,f,p); }
__global__ __launch_bounds__(THREADS, 8) void g_v2hit (ARGS) { gather_body<2>(a,b,c,d,e,f,p); }
__global__ __launch_bounds__(THREADS, 8) void g_v3nop (ARGS) { gather_body<3>(a,b,c,d,e,f,p); }

// combine halves + ReLU + classifier (reads region 0 = g_real's output)
__global__ __launch_bounds__(256) void gnn_head(
    const float* __restrict__ partial, const float* __restrict__ Wm,
    const float* __restrict__ bv, float* __restrict__ out)
{
    __shared__ float pooled[DIM];
    const int g   = blockIdx.x;
    const int tid = threadIdx.x;

    if (tid < DIM) {
        float s = partial[g * DIM + tid] + partial[(NGRAPH + g) * DIM + tid];
        pooled[tid] = fmaxf(s, 0.0f);
    }
    __syncthreads();

    if (tid < NCLS) {
        float acc = bv[tid];
        #pragma unroll 4
        for (int k = 0; k < DIM; ++k)
            acc += pooled[k] * Wm[k * NCLS + tid];
        out[g * NCLS + tid] = acc;
    }
}

extern "C" void kernel_launch(void* const* d_in, const int* in_sizes, int n_in,
                              void* d_out, int out_size, void* d_ws, size_t ws_size,
                              hipStream_t stream) {
    const float* node_emb = (const float*)d_in[0];
    const float* edge_w   = (const float*)d_in[1];
    const float* Wm       = (const float*)d_in[2];
    const float* bv       = (const float*)d_in[3];
    const int*   node_ids = (const int*)d_in[4];
    const int*   edge_src = (const int*)d_in[5];
    const int*   edge_dst = (const int*)d_in[6];
    const int*   edge_ids = (const int*)d_in[7];

    float* partial = (float*)d_ws;   // 4 regions x 512 x DIM floats = 1.64 MB

    // ablation variants first (scratch regions 1..3), then the real pass
    g_v1full<<<2 * NGRAPH, THREADS, 0, stream>>>(node_emb, edge_w, node_ids,
                                                 edge_src, edge_dst, edge_ids, partial);
    g_v2hit <<<2 * NGRAPH, THREADS, 0, stream>>>(node_emb, edge_w, node_ids,
                                                 edge_src, edge_dst, edge_ids, partial);
    g_v3nop <<<2 * NGRAPH, THREADS, 0, stream>>>(node_emb, edge_w, node_ids,
                                                 edge_src, edge_dst, edge_ids, partial);
    g_real  <<<2 * NGRAPH, THREADS, 0, stream>>>(node_emb, edge_w, node_ids,
                                                 edge_src, edge_dst, edge_ids, partial);
    gnn_head<<<NGRAPH, 256, 0, stream>>>(partial, Wm, bv, (float*)d_out);
}